// Round 4
// baseline (1443.150 us; speedup 1.0000x reference)
//
#include <hip/hip_runtime.h>
#include <hip/hip_bf16.h>
#include <cstdint>
#include <cstddef>

typedef unsigned short u16;
using short8  = __attribute__((ext_vector_type(8))) short;
using floatx4 = __attribute__((ext_vector_type(4))) float;

typedef __attribute__((address_space(1))) void gvoid;
typedef __attribute__((address_space(3))) void svoid;

__device__ __forceinline__ u16 f2bf(float f) {
  __hip_bfloat16 h = __float2bfloat16(f);
  return __builtin_bit_cast(u16, h);
}

__device__ __forceinline__ floatx4 mfma16(short8 a, short8 b, floatx4 c) {
  return __builtin_amdgcn_mfma_f32_16x16x32_bf16(a, b, c, 0, 0, 0);
}

// async 16B/lane global->LDS; lds base must be wave-uniform (lane i lands at base + i*16B)
__device__ __forceinline__ void glds16(const u16* g, u16* l) {
  __builtin_amdgcn_global_load_lds((gvoid*)g, (svoid*)l, 16, 0, 0);
}

// ---------------------------------------------------------------------------
// pe table: per (l, j) cos/sin.  j<16: x=l%32 rotations; j>=16: y=l/32.
__global__ void pe_kernel(float* __restrict__ pet) {
  int t = blockIdx.x * 256 + threadIdx.x;   // 1024*32
  if (t >= 32768) return;
  int l = t >> 5, j = t & 31;
  float pos   = (j < 16) ? (float)(l & 31) : (float)(l >> 5);
  float omega = powf(10000.f, -(float)(j & 15) / 16.f);
  float a = pos * omega;
  pet[2 * t]     = cosf(a);
  pet[2 * t + 1] = sinf(a);
}

// ---------------------------------------------------------------------------
// weight transpose + bf16 cast: in fp32 (K,N) row-major -> out bf16 (N,K)
// blockIdx.z = layer (stride K*N elements both sides)
__global__ __launch_bounds__(256) void twt_kernel(const float* __restrict__ in,
                                                  u16* __restrict__ out, int K, int N) {
  size_t lofs = (size_t)blockIdx.z * K * N;
  in  += lofs;
  out += lofs;
  __shared__ float tile[32][33];
  int bx = blockIdx.x;           // over N
  int by = blockIdx.y;           // over K
  int tx = threadIdx.x & 31, ty = threadIdx.x >> 5;  // 32 x 8
  #pragma unroll
  for (int p = 0; p < 4; p++) {
    int k = by * 32 + ty + p * 8;
    tile[ty + p * 8][tx] = in[(size_t)k * N + bx * 32 + tx];
  }
  __syncthreads();
  #pragma unroll
  for (int p = 0; p < 4; p++) {
    int n = bx * 32 + ty + p * 8;
    out[(size_t)n * K + by * 32 + tx] = f2bf(tile[tx][ty + p * 8]);
  }
}

// fp32 -> bf16 elementwise
__global__ void cvt_kernel(const float* __restrict__ in, u16* __restrict__ out, int n) {
  int i = blockIdx.x * 256 + threadIdx.x;
  if (i < n) out[i] = f2bf(in[i]);
}

// cond projection, stage 1: partial[chunk][b][d] over 96-k chunks
__global__ __launch_bounds__(256) void condp_kernel(const float* __restrict__ ce,
                                                    const float* __restrict__ w,
                                                    float* __restrict__ partial) {
  int d = blockIdx.x * 256 + threadIdx.x;  // 768
  int c = blockIdx.y;                      // 16
  #pragma unroll
  for (int b = 0; b < 2; b++) {
    float acc = 0.f;
    #pragma unroll 4
    for (int k = c * 96; k < c * 96 + 96; k++) acc += ce[b * 1536 + k] * w[(size_t)k * 768 + d];
    partial[(size_t)(c * 2 + b) * 768 + d] = acc;
  }
}

// cond projection, stage 2: reduce 16 partials + bias
__global__ __launch_bounds__(256) void condr_kernel(const float* __restrict__ partial,
                                                    const float* __restrict__ bias,
                                                    float* __restrict__ out) {
  int t = blockIdx.x * 256 + threadIdx.x;  // 1536
  int b = t / 768, d = t % 768;
  float acc = bias[d];
  #pragma unroll
  for (int c = 0; c < 16; c++) acc += partial[(size_t)(c * 2 + b) * 768 + d];
  out[b * 768 + d] = acc;
}

// ---------------------------------------------------------------------------
// layernorm: x fp32 (rows,768) -> out bf16
__global__ __launch_bounds__(256) void ln_kernel(const float* __restrict__ x,
                                                 const float* __restrict__ g,
                                                 const float* __restrict__ b,
                                                 u16* __restrict__ out) {
  int row = blockIdx.x;
  const float* xr = x + (size_t)row * 768;
  int t = threadIdx.x;
  float v0 = xr[t], v1 = xr[t + 256], v2 = xr[t + 512];
  float s = v0 + v1 + v2, s2 = v0 * v0 + v1 * v1 + v2 * v2;
  #pragma unroll
  for (int o = 32; o >= 1; o >>= 1) { s += __shfl_xor(s, o); s2 += __shfl_xor(s2, o); }
  __shared__ float red[8];
  int w = t >> 6, lane = t & 63;
  if (lane == 0) { red[w] = s; red[4 + w] = s2; }
  __syncthreads();
  s  = red[0] + red[1] + red[2] + red[3];
  s2 = red[4] + red[5] + red[6] + red[7];
  float mean = s * (1.f / 768.f);
  float var  = s2 * (1.f / 768.f) - mean * mean;
  float rstd = rsqrtf(var + 1e-5f);
  u16* orow = out + (size_t)row * 768;
  orow[t]       = f2bf((v0 - mean) * rstd * g[t] + b[t]);
  orow[t + 256] = f2bf((v1 - mean) * rstd * g[t + 256] + b[t + 256]);
  orow[t + 512] = f2bf((v2 - mean) * rstd * g[t + 512] + b[t + 512]);
}

// ---------------------------------------------------------------------------
// rmsnorm + rope on q,k.  One 64-lane group per (b,l,h).  attn_scale folded into q.
__global__ __launch_bounds__(256) void ropeq_kernel(const float* __restrict__ qkv,
                                                    const float* __restrict__ qs,
                                                    const float* __restrict__ ks,
                                                    const float* __restrict__ pet,
                                                    u16* __restrict__ qb, u16* __restrict__ kb) {
  int gid = blockIdx.x * 4 + (threadIdx.x >> 6);  // (b*1024+l)*12 + h
  int lane = threadIdx.x & 63;
  int h = gid % 12, bl = gid / 12;
  int l = bl & 1023, b = bl >> 10;
  const float* qp = qkv + ((size_t)(b * 1024 + l) * 3 + 0) * 768 + h * 64;
  const float* kp = qp + 768;
  float q = qp[lane], k = kp[lane];
  float sq = q * q, sk = k * k;
  #pragma unroll
  for (int o = 1; o < 64; o <<= 1) { sq += __shfl_xor(sq, o); sk += __shfl_xor(sk, o); }
  q *= rsqrtf(sq * (1.f / 64.f) + 1e-6f) * qs[lane];
  k *= rsqrtf(sk * (1.f / 64.f) + 1e-6f) * ks[lane];
  int j = lane >> 1;
  float c = pet[(l * 32 + j) * 2], s = pet[(l * 32 + j) * 2 + 1];
  float qo = __shfl_xor(q, 1), ko = __shfl_xor(k, 1);
  float qr = (lane & 1) ? (s * qo + c * q) : (c * q - s * qo);
  float kr = (lane & 1) ? (s * ko + c * k) : (c * k - s * ko);
  int bh = b * 12 + h;
  qb[((size_t)bh * 1024 + l) * 64 + lane] = f2bf(qr * 0.125f);
  kb[((size_t)bh * 1024 + l) * 64 + lane] = f2bf(kr);
}

// v: (b,l,h,d) slice of qkv -> vt bf16 (bh, d, l)
__global__ __launch_bounds__(256) void vtrans_kernel(const float* __restrict__ qkv,
                                                     u16* __restrict__ vt) {
  int lt = blockIdx.x, bh = blockIdx.y;
  int b = bh / 12, h = bh % 12;
  __shared__ float tile[64][65];
  int t = threadIdx.x, c = t & 63, r0 = t >> 6;
  #pragma unroll
  for (int p = 0; p < 16; p++) {
    int lr = p * 4 + r0;
    tile[lr][c] = qkv[((size_t)(b * 1024 + lt * 64 + lr) * 3 + 2) * 768 + h * 64 + c];
  }
  __syncthreads();
  #pragma unroll
  for (int p = 0; p < 16; p++) {
    int d = p * 4 + r0;
    vt[((size_t)bh * 64 + d) * 1024 + lt * 64 + c] = f2bf(tile[c][d]);
  }
}

// ---------------------------------------------------------------------------
// flash attention, split-KV, FIXED-SHIFT softmax (scores provably in [-8,8]
// after rmsnorm: |q_scaled|<=1, |k|<=8 => p=exp(s-8)<=1, no running max).
// grid (qt, bh, split); block: 64 q rows x 256 kv; 4 waves, wave owns 16 q rows.
// Writes unnormalized partial O (fp32) + row sums pl.
__global__ __launch_bounds__(256) void attn_split(const u16* __restrict__ qb,
                                                  const u16* __restrict__ kbuf,
                                                  const u16* __restrict__ vt,
                                                  float* __restrict__ po,
                                                  float* __restrict__ pl) {
  const int qt = blockIdx.x, bh = blockIdx.y, sp = blockIdx.z;
  const int lane = threadIdx.x & 63, w = threadIdx.x >> 6;
  const int quad = lane >> 4, l16 = lane & 15;
  // P tile: 16 rows x 128 cols, row stride 136 u16 (272B, 16B aligned, conflict-free)
  __shared__ __align__(16) u16 Ps[4][16 * 136];
  const u16* Q  = qb   + (size_t)bh * 1024 * 64;
  const u16* Kp = kbuf + (size_t)bh * 1024 * 64;
  const u16* Vp = vt   + (size_t)bh * 64 * 1024;
  const int qrow0 = qt * 64 + w * 16;
  short8 aq0, aq1;
  {
    const u16* qp = Q + (size_t)(qrow0 + l16) * 64 + quad * 8;
    aq0 = *(const short8*)qp;
    aq1 = *(const short8*)(qp + 32);
  }
  floatx4 accO[4];
  #pragma unroll
  for (int i = 0; i < 4; i++) accO[i] = (floatx4){0.f, 0.f, 0.f, 0.f};
  float lsum[4] = {0.f, 0.f, 0.f, 0.f};   // per-lane partial row sums (cols n*16+l16)

  #pragma unroll
  for (int nt = 0; nt < 2; ++nt) {
    const int kb0 = sp * 256 + nt * 128;
    floatx4 s[8];
    #pragma unroll
    for (int n = 0; n < 8; n++) {
      const u16* kp = Kp + (size_t)(kb0 + n * 16 + l16) * 64 + quad * 8;
      short8 b0 = *(const short8*)kp;
      short8 b1 = *(const short8*)(kp + 32);
      floatx4 z = (floatx4){0.f, 0.f, 0.f, 0.f};
      z = mfma16(aq0, b0, z);
      s[n] = mfma16(aq1, b1, z);
    }
    // p = exp(s - 8); accumulate per-lane row-sum partials; no cross-lane ops here
    #pragma unroll
    for (int n = 0; n < 8; n++) {
      #pragma unroll
      for (int r = 0; r < 4; r++) {
        float pv = __expf(s[n][r] - 8.f);
        lsum[r] += pv;
        Ps[w][(quad * 4 + r) * 136 + n * 16 + l16] = f2bf(pv);
      }
    }
    #pragma unroll
    for (int kt = 0; kt < 4; kt++) {
      short8 ap = *(const short8*)&Ps[w][l16 * 136 + kt * 32 + quad * 8];
      #pragma unroll
      for (int dt = 0; dt < 4; dt++) {
        const u16* vp = Vp + (size_t)(dt * 16 + l16) * 1024 + kb0 + kt * 32 + quad * 8;
        short8 bv = *(const short8*)vp;
        accO[dt] = mfma16(ap, bv, accO[dt]);
      }
    }
  }
  // one reduce at the end: sum lsum across the 16 lanes of each quad-row group
  #pragma unroll
  for (int r = 0; r < 4; r++) {
    #pragma unroll
    for (int o = 1; o < 16; o <<= 1) lsum[r] += __shfl_xor(lsum[r], o);
  }
  const size_t sb = (size_t)(sp * 24 + bh) * 1024;
  #pragma unroll
  for (int r = 0; r < 4; r++) {
    int lr = qrow0 + quad * 4 + r;
    if (l16 == 0) pl[sb + lr] = lsum[r];
    #pragma unroll
    for (int dt = 0; dt < 4; dt++)
      po[(sb + lr) * 64 + dt * 16 + l16] = accO[dt][r];
  }
}

// combine 4 splits (plain sums; fixed shift means no max merge): wave per row.
__global__ __launch_bounds__(256) void attn_comb(const float* __restrict__ po,
                                                 const float* __restrict__ pl,
                                                 u16* __restrict__ obuf) {
  int w = threadIdx.x >> 6, lane = threadIdx.x & 63;
  int gr = blockIdx.x * 4 + w;            // [0, 24576)
  int bh = gr >> 10, l = gr & 1023;
  float num = 0.f, den = 0.f;
  #pragma unroll
  for (int s = 0; s < 4; s++) {
    num += po[((size_t)(s * 24 + bh) * 1024 + l) * 64 + lane];
    den += pl[(size_t)(s * 24 + bh) * 1024 + l];
  }
  int b = bh / 12, h = bh % 12;
  obuf[((size_t)(b * 1024 + l)) * 768 + h * 64 + lane] = f2bf(num / den);
}

// ---------------------------------------------------------------------------
// GEMM: C(M,N) = A(M,K) @ Bt(N,K)^T, bf16 in, fp32 acc.
// Tile 64(M) x BN(N) x 32(K); 4 waves, each computes 32 x BN/2.
// EPI 0: +bias -> Cf (or Cb).  1: +bias +cond[row>>10] -> Cf.
// EPI 2: +bias +extra[row,col] -> Cf and Cb.  3: gelu(+bias) -> Cb.
template <int EPI, int BN>
__global__ __launch_bounds__(256) void gemm_bt(const u16* __restrict__ A,
                                               const u16* __restrict__ Bt,
                                               const float* __restrict__ bias,
                                               const float* extra,
                                               float* Cf, u16* Cb, int M, int N, int K) {
  constexpr int ROWS = 64 + BN;
  constexpr int NTW  = BN / 32;        // n-frags per wave
  constexpr int PC   = ROWS / 64;      // staging chunks per wave
  __shared__ __align__(16) u16 S[ROWS * 32];
  u16* As = S;
  u16* Bs = S + 64 * 32;
  const int t = threadIdx.x;
  const int lane = t & 63, w = t >> 6;
  const int quad = lane >> 4, l16 = lane & 15;
  const int m0 = blockIdx.y * 64, n0 = blockIdx.x * BN;
  const int wm = (w >> 1) * 32, wn = (w & 1) * (BN / 2);
  floatx4 acc[2][NTW];
  #pragma unroll
  for (int i = 0; i < 2; i++)
    #pragma unroll
    for (int j = 0; j < NTW; j++) acc[i][j] = (floatx4){0.f, 0.f, 0.f, 0.f};

  // staging: ROWS/16 chunks of 16 rows x 32 cols; chunk c<4 -> A rows, else B rows.
  const u16* gp[PC];
  u16* lp[PC];
  #pragma unroll
  for (int j = 0; j < PC; j++) {
    int c = w * PC + j;
    int r = lane >> 2;
    const u16* base = (c < 4) ? (A + (size_t)(m0 + c * 16 + r) * K)
                              : (Bt + (size_t)(n0 + (c - 4) * 16 + r) * K);
    gp[j] = base + (lane & 3) * 8;
    lp[j] = S + c * 16 * 32;
  }

  for (int k0 = 0; k0 < K; k0 += 32) {
    #pragma unroll
    for (int j = 0; j < PC; j++) glds16(gp[j] + k0, lp[j]);
    __syncthreads();
    short8 af[2], bfr[NTW];
    #pragma unroll
    for (int mt = 0; mt < 2; mt++)
      af[mt] = *(const short8*)&As[(wm + mt * 16 + l16) * 32 + quad * 8];
    #pragma unroll
    for (int nt = 0; nt < NTW; nt++)
      bfr[nt] = *(const short8*)&Bs[(wn + nt * 16 + l16) * 32 + quad * 8];
    #pragma unroll
    for (int mt = 0; mt < 2; mt++)
      #pragma unroll
      for (int nt = 0; nt < NTW; nt++)
        acc[mt][nt] = mfma16(af[mt], bfr[nt], acc[mt][nt]);
    __syncthreads();
  }

  #pragma unroll
  for (int mt = 0; mt < 2; mt++) {
    #pragma unroll
    for (int nt = 0; nt < NTW; nt++) {
      int col = n0 + wn + nt * 16 + l16;
      float bcol = bias ? bias[col] : 0.f;
      #pragma unroll
      for (int r = 0; r < 4; r++) {
        int row = m0 + wm + mt * 16 + quad * 4 + r;
        float v = acc[mt][nt][r] + bcol;
        if (EPI == 1) v += extra[(row >> 10) * N + col];
        if (EPI == 2) v += extra[(size_t)row * N + col];
        if (EPI == 3) v = 0.5f * v * (1.f + erff(v * 0.70710678118654752f));
        if (Cf) Cf[(size_t)row * N + col] = v;
        if (Cb) Cb[(size_t)row * N + col] = f2bf(v);
      }
    }
  }
}

// ---------------------------------------------------------------------------
extern "C" void kernel_launch(void* const* d_in, const int* in_sizes, int n_in,
                              void* d_out, int out_size, void* d_ws, size_t ws_size,
                              hipStream_t stream) {
  const float* sf   = (const float*)d_in[0];
  const float* ce   = (const float*)d_in[2];
  const float* sw   = (const float*)d_in[3];
  const float* sb   = (const float*)d_in[4];
  const float* cw   = (const float*)d_in[5];
  const float* cb   = (const float*)d_in[6];
  const float* ln1g = (const float*)d_in[7];
  const float* ln1b = (const float*)d_in[8];
  const float* qkvw = (const float*)d_in[9];
  const float* qsc  = (const float*)d_in[10];
  const float* ksc  = (const float*)d_in[11];
  const float* pw   = (const float*)d_in[12];
  const float* pb   = (const float*)d_in[13];
  const float* ln2g = (const float*)d_in[16];
  const float* ln2b = (const float*)d_in[17];
  const float* w1   = (const float*)d_in[18];
  const float* b1   = (const float*)d_in[19];
  const float* w2   = (const float*)d_in[20];
  const float* b2   = (const float*)d_in[21];
  const float* ow   = (const float*)d_in[22];
  const float* ob   = (const float*)d_in[23];

  char* p = (char*)d_ws;
  auto alloc = [&](size_t bytes) { char* r = p; p += (bytes + 255) & ~(size_t)255; return r; };
  float* pet  = (float*)alloc((size_t)1024 * 32 * 2 * 4);
  u16* swT    = (u16*)alloc((size_t)768 * 768 * 2);
  u16* owT    = (u16*)alloc((size_t)768 * 768 * 2);
  u16* qkvT   = (u16*)alloc((size_t)6 * 2304 * 768 * 2);
  u16* pwT    = (u16*)alloc((size_t)6 * 768 * 768 * 2);
  u16* w1T    = (u16*)alloc((size_t)6 * 3072 * 768 * 2);
  u16* w2T    = (u16*)alloc((size_t)6 * 768 * 3072 * 2);
  u16* sfb    = (u16*)alloc((size_t)2048 * 768 * 2);
  float* cpar = (float*)alloc((size_t)32 * 768 * 4);
  float* cond = (float*)alloc((size_t)2 * 768 * 4);
  float* x    = (float*)alloc((size_t)2048 * 768 * 4);
  u16* xb     = (u16*)alloc((size_t)2048 * 768 * 2);
  u16* h      = (u16*)alloc((size_t)2048 * 768 * 2);
  float* qkv  = (float*)alloc((size_t)2048 * 2304 * 4);
  u16* qbuf   = (u16*)alloc((size_t)2048 * 768 * 2);
  u16* kbuf   = (u16*)alloc((size_t)2048 * 768 * 2);
  u16* vtb    = (u16*)alloc((size_t)2048 * 768 * 2);
  u16* obuf   = (u16*)alloc((size_t)2048 * 768 * 2);
  u16* gbuf   = (u16*)alloc((size_t)2048 * 3072 * 2);
  float* po   = (float*)alloc((size_t)4 * 24 * 1024 * 64 * 4);
  float* pl   = (float*)alloc((size_t)4 * 24 * 1024 * 4);

  pe_kernel<<<128, 256, 0, stream>>>(pet);
  twt_kernel<<<dim3(24, 24, 1), 256, 0, stream>>>(sw, swT, 768, 768);
  twt_kernel<<<dim3(24, 24, 1), 256, 0, stream>>>(ow, owT, 768, 768);
  twt_kernel<<<dim3(72, 24, 6), 256, 0, stream>>>(qkvw, qkvT, 768, 2304);
  twt_kernel<<<dim3(24, 24, 6), 256, 0, stream>>>(pw, pwT, 768, 768);
  twt_kernel<<<dim3(96, 24, 6), 256, 0, stream>>>(w1, w1T, 768, 3072);
  twt_kernel<<<dim3(24, 96, 6), 256, 0, stream>>>(w2, w2T, 3072, 768);
  cvt_kernel<<<(2048 * 768) / 256, 256, 0, stream>>>(sf, sfb, 2048 * 768);
  condp_kernel<<<dim3(3, 16), 256, 0, stream>>>(ce, cw, cpar);
  condr_kernel<<<6, 256, 0, stream>>>(cpar, cb, cond);

  gemm_bt<1, 64><<<dim3(12, 32), 256, 0, stream>>>(sfb, swT, sb, cond, x, nullptr, 2048, 768, 768);

  for (int i = 0; i < 6; i++) {
    ln_kernel<<<2048, 256, 0, stream>>>(x, ln1g + i * 768, ln1b + i * 768, h);
    gemm_bt<0, 128><<<dim3(18, 32), 256, 0, stream>>>(h, qkvT + (size_t)i * 2304 * 768,
                                                      nullptr, nullptr, qkv, nullptr, 2048, 2304, 768);
    ropeq_kernel<<<6144, 256, 0, stream>>>(qkv, qsc + i * 64, ksc + i * 64, pet, qbuf, kbuf);
    vtrans_kernel<<<dim3(16, 24), 256, 0, stream>>>(qkv, vtb);
    attn_split<<<dim3(16, 24, 4), 256, 0, stream>>>(qbuf, kbuf, vtb, po, pl);
    attn_comb<<<6144, 256, 0, stream>>>(po, pl, obuf);
    gemm_bt<2, 64><<<dim3(12, 32), 256, 0, stream>>>(obuf, pwT + (size_t)i * 768 * 768,
                                                     pb + i * 768, x, x, xb, 2048, 768, 768);
    ln_kernel<<<2048, 256, 0, stream>>>(x, ln2g + i * 768, ln2b + i * 768, h);
    gemm_bt<3, 128><<<dim3(24, 32), 256, 0, stream>>>(h, w1T + (size_t)i * 3072 * 768,
                                                      b1 + i * 3072, nullptr, nullptr, gbuf, 2048, 3072, 768);
    gemm_bt<2, 64><<<dim3(12, 32), 256, 0, stream>>>(gbuf, w2T + (size_t)i * 768 * 3072,
                                                     b2 + i * 768, x, x, xb, 2048, 768, 3072);
  }
  gemm_bt<0, 64><<<dim3(12, 32), 256, 0, stream>>>(xb, owT, ob, nullptr, (float*)d_out, nullptr,
                                                   2048, 768, 768);
}

// Round 5
// 1197.673 us; speedup vs baseline: 1.2050x; 1.2050x over previous
//
#include <hip/hip_runtime.h>
#include <hip/hip_bf16.h>
#include <cstdint>
#include <cstddef>

typedef unsigned short u16;
using short8  = __attribute__((ext_vector_type(8))) short;
using floatx4 = __attribute__((ext_vector_type(4))) float;

typedef __attribute__((address_space(1))) void gvoid;
typedef __attribute__((address_space(3))) void svoid;

__device__ __forceinline__ u16 f2bf(float f) {
  __hip_bfloat16 h = __float2bfloat16(f);
  return __builtin_bit_cast(u16, h);
}

__device__ __forceinline__ floatx4 mfma16(short8 a, short8 b, floatx4 c) {
  return __builtin_amdgcn_mfma_f32_16x16x32_bf16(a, b, c, 0, 0, 0);
}

// async 16B/lane global->LDS; lds base must be wave-uniform (lane i lands at base + i*16B)
__device__ __forceinline__ void glds16(const u16* g, u16* l) {
  __builtin_amdgcn_global_load_lds((gvoid*)g, (svoid*)l, 16, 0, 0);
}

// ---------------------------------------------------------------------------
// pe table: per (l, j) cos/sin.  j<16: x=l%32 rotations; j>=16: y=l/32.
__global__ void pe_kernel(float* __restrict__ pet) {
  int t = blockIdx.x * 256 + threadIdx.x;   // 1024*32
  if (t >= 32768) return;
  int l = t >> 5, j = t & 31;
  float pos   = (j < 16) ? (float)(l & 31) : (float)(l >> 5);
  float omega = powf(10000.f, -(float)(j & 15) / 16.f);
  float a = pos * omega;
  pet[2 * t]     = cosf(a);
  pet[2 * t + 1] = sinf(a);
}

// ---------------------------------------------------------------------------
// weight transpose + bf16 cast: in fp32 (K,N) row-major -> out bf16 (N,K)
// blockIdx.z = layer (stride K*N elements both sides)
__global__ __launch_bounds__(256) void twt_kernel(const float* __restrict__ in,
                                                  u16* __restrict__ out, int K, int N) {
  size_t lofs = (size_t)blockIdx.z * K * N;
  in  += lofs;
  out += lofs;
  __shared__ float tile[32][33];
  int bx = blockIdx.x;           // over N
  int by = blockIdx.y;           // over K
  int tx = threadIdx.x & 31, ty = threadIdx.x >> 5;  // 32 x 8
  #pragma unroll
  for (int p = 0; p < 4; p++) {
    int k = by * 32 + ty + p * 8;
    tile[ty + p * 8][tx] = in[(size_t)k * N + bx * 32 + tx];
  }
  __syncthreads();
  #pragma unroll
  for (int p = 0; p < 4; p++) {
    int n = bx * 32 + ty + p * 8;
    out[(size_t)n * K + by * 32 + tx] = f2bf(tile[tx][ty + p * 8]);
  }
}

// fp32 -> bf16 elementwise
__global__ void cvt_kernel(const float* __restrict__ in, u16* __restrict__ out, int n) {
  int i = blockIdx.x * 256 + threadIdx.x;
  if (i < n) out[i] = f2bf(in[i]);
}

// cond projection, stage 1: partial[chunk][b][d] over 96-k chunks
__global__ __launch_bounds__(256) void condp_kernel(const float* __restrict__ ce,
                                                    const float* __restrict__ w,
                                                    float* __restrict__ partial) {
  int d = blockIdx.x * 256 + threadIdx.x;  // 768
  int c = blockIdx.y;                      // 16
  #pragma unroll
  for (int b = 0; b < 2; b++) {
    float acc = 0.f;
    #pragma unroll 4
    for (int k = c * 96; k < c * 96 + 96; k++) acc += ce[b * 1536 + k] * w[(size_t)k * 768 + d];
    partial[(size_t)(c * 2 + b) * 768 + d] = acc;
  }
}

// cond projection, stage 2: reduce 16 partials + bias
__global__ __launch_bounds__(256) void condr_kernel(const float* __restrict__ partial,
                                                    const float* __restrict__ bias,
                                                    float* __restrict__ out) {
  int t = blockIdx.x * 256 + threadIdx.x;  // 1536
  int b = t / 768, d = t % 768;
  float acc = bias[d];
  #pragma unroll
  for (int c = 0; c < 16; c++) acc += partial[(size_t)(c * 2 + b) * 768 + d];
  out[b * 768 + d] = acc;
}

// ---------------------------------------------------------------------------
// layernorm: x fp32 (rows,768) -> out bf16
__global__ __launch_bounds__(256) void ln_kernel(const float* __restrict__ x,
                                                 const float* __restrict__ g,
                                                 const float* __restrict__ b,
                                                 u16* __restrict__ out) {
  int row = blockIdx.x;
  const float* xr = x + (size_t)row * 768;
  int t = threadIdx.x;
  float v0 = xr[t], v1 = xr[t + 256], v2 = xr[t + 512];
  float s = v0 + v1 + v2, s2 = v0 * v0 + v1 * v1 + v2 * v2;
  #pragma unroll
  for (int o = 32; o >= 1; o >>= 1) { s += __shfl_xor(s, o); s2 += __shfl_xor(s2, o); }
  __shared__ float red[8];
  int w = t >> 6, lane = t & 63;
  if (lane == 0) { red[w] = s; red[4 + w] = s2; }
  __syncthreads();
  s  = red[0] + red[1] + red[2] + red[3];
  s2 = red[4] + red[5] + red[6] + red[7];
  float mean = s * (1.f / 768.f);
  float var  = s2 * (1.f / 768.f) - mean * mean;
  float rstd = rsqrtf(var + 1e-5f);
  u16* orow = out + (size_t)row * 768;
  orow[t]       = f2bf((v0 - mean) * rstd * g[t] + b[t]);
  orow[t + 256] = f2bf((v1 - mean) * rstd * g[t + 256] + b[t + 256]);
  orow[t + 512] = f2bf((v2 - mean) * rstd * g[t + 512] + b[t + 512]);
}

// ---------------------------------------------------------------------------
// rmsnorm + rope on q,k.  One 64-lane group per (b,l,h).  attn_scale folded into q.
__global__ __launch_bounds__(256) void ropeq_kernel(const float* __restrict__ qkv,
                                                    const float* __restrict__ qs,
                                                    const float* __restrict__ ks,
                                                    const float* __restrict__ pet,
                                                    u16* __restrict__ qb, u16* __restrict__ kb) {
  int gid = blockIdx.x * 4 + (threadIdx.x >> 6);  // (b*1024+l)*12 + h
  int lane = threadIdx.x & 63;
  int h = gid % 12, bl = gid / 12;
  int l = bl & 1023, b = bl >> 10;
  const float* qp = qkv + ((size_t)(b * 1024 + l) * 3 + 0) * 768 + h * 64;
  const float* kp = qp + 768;
  float q = qp[lane], k = kp[lane];
  float sq = q * q, sk = k * k;
  #pragma unroll
  for (int o = 1; o < 64; o <<= 1) { sq += __shfl_xor(sq, o); sk += __shfl_xor(sk, o); }
  q *= rsqrtf(sq * (1.f / 64.f) + 1e-6f) * qs[lane];
  k *= rsqrtf(sk * (1.f / 64.f) + 1e-6f) * ks[lane];
  int j = lane >> 1;
  float c = pet[(l * 32 + j) * 2], s = pet[(l * 32 + j) * 2 + 1];
  float qo = __shfl_xor(q, 1), ko = __shfl_xor(k, 1);
  float qr = (lane & 1) ? (s * qo + c * q) : (c * q - s * qo);
  float kr = (lane & 1) ? (s * ko + c * k) : (c * k - s * ko);
  int bh = b * 12 + h;
  qb[((size_t)bh * 1024 + l) * 64 + lane] = f2bf(qr * 0.125f);
  kb[((size_t)bh * 1024 + l) * 64 + lane] = f2bf(kr);
}

// v: (b,l,h,d) slice of qkv -> vt bf16 (bh, d, l)
__global__ __launch_bounds__(256) void vtrans_kernel(const float* __restrict__ qkv,
                                                     u16* __restrict__ vt) {
  int lt = blockIdx.x, bh = blockIdx.y;
  int b = bh / 12, h = bh % 12;
  __shared__ float tile[64][65];
  int t = threadIdx.x, c = t & 63, r0 = t >> 6;
  #pragma unroll
  for (int p = 0; p < 16; p++) {
    int lr = p * 4 + r0;
    tile[lr][c] = qkv[((size_t)(b * 1024 + lt * 64 + lr) * 3 + 2) * 768 + h * 64 + c];
  }
  __syncthreads();
  #pragma unroll
  for (int p = 0; p < 16; p++) {
    int d = p * 4 + r0;
    vt[((size_t)bh * 64 + d) * 1024 + lt * 64 + c] = f2bf(tile[c][d]);
  }
}

// ---------------------------------------------------------------------------
// flash attention, split-KV, fixed-shift softmax (scores in [-8,8] after rmsnorm),
// block-shared LDS staging of K/V via global_load_lds with XOR chunk swizzle.
// grid (qt, bh, split=2); block: 64 q rows x 512 kv (4 tiles of 128).
// 4 waves, wave owns 16 q rows.  Writes unnormalized partial O + row sums.
__global__ __launch_bounds__(256) void attn_split(const u16* __restrict__ qb,
                                                  const u16* __restrict__ kbuf,
                                                  const u16* __restrict__ vt,
                                                  float* __restrict__ po,
                                                  float* __restrict__ pl) {
  const int qt = blockIdx.x, bh = blockIdx.y, sp = blockIdx.z;
  const int lane = threadIdx.x & 63, w = threadIdx.x >> 6;
  const int quad = lane >> 4, l16 = lane & 15;
  // K tile 128x64 u16, slot(r, c8) = global chunk c8^(r&7)     (16 KB)
  // V tile 64x128 u16, slot(r, c16)= global chunk c16^(r&15)   (16 KB)
  // Ps: per-wave 16x136 u16 (padded, conflict-free)            (17 KB)
  __shared__ __align__(16) u16 Ks[128 * 64];
  __shared__ __align__(16) u16 Vs[64 * 128];
  __shared__ __align__(16) u16 Ps[4][16 * 136];
  const u16* Q  = qb   + (size_t)bh * 1024 * 64;
  const u16* Kp = kbuf + (size_t)bh * 1024 * 64;
  const u16* Vp = vt   + (size_t)bh * 64 * 1024;
  const int qrow0 = qt * 64 + w * 16;
  short8 aq0, aq1;
  {
    const u16* qp = Q + (size_t)(qrow0 + l16) * 64 + quad * 8;
    aq0 = *(const short8*)qp;
    aq1 = *(const short8*)(qp + 32);
  }
  floatx4 accO[4];
  #pragma unroll
  for (int i = 0; i < 4; i++) accO[i] = (floatx4){0.f, 0.f, 0.f, 0.f};
  float lsum[4] = {0.f, 0.f, 0.f, 0.f};

  // staging address precompute (wave w stages K rows [w*32,w*32+32), V rows [w*16,w*16+16))
  const int krow_in = (lane >> 3);          // 0..7 within 8-row group
  const int kchunk  = lane & 7;
  const int vrow_in = (lane >> 4);          // 0..3 within 4-row group
  const int vchunk  = lane & 15;

  for (int nt = 0; nt < 4; ++nt) {
    const int kb0 = sp * 512 + nt * 128;
    __syncthreads();   // prior iteration's LDS readers done
    #pragma unroll
    for (int j = 0; j < 4; j++) {
      int r = w * 32 + j * 8 + krow_in;
      int g = kchunk ^ (r & 7);
      glds16(Kp + (size_t)(kb0 + r) * 64 + g * 8, Ks + (w * 32 + j * 8) * 64);
    }
    #pragma unroll
    for (int j = 0; j < 4; j++) {
      int r = w * 16 + j * 4 + vrow_in;
      int g = vchunk ^ (r & 15);
      glds16(Vp + (size_t)r * 1024 + kb0 + g * 8, Vs + (w * 16 + j * 4) * 128);
    }
    __syncthreads();   // staging complete (compiler emits vmcnt(0) before barrier)

    floatx4 s[8];
    #pragma unroll
    for (int n = 0; n < 8; n++) {
      int row = n * 16 + l16;
      int c0 = quad ^ (l16 & 7);
      short8 b0 = *(const short8*)&Ks[row * 64 + c0 * 8];
      short8 b1 = *(const short8*)&Ks[row * 64 + (c0 ^ 4) * 8];
      floatx4 z = (floatx4){0.f, 0.f, 0.f, 0.f};
      z = mfma16(aq0, b0, z);
      s[n] = mfma16(aq1, b1, z);
    }
    #pragma unroll
    for (int n = 0; n < 8; n++) {
      #pragma unroll
      for (int r = 0; r < 4; r++) {
        float pv = __expf(s[n][r] - 8.f);
        lsum[r] += pv;
        Ps[w][(quad * 4 + r) * 136 + n * 16 + l16] = f2bf(pv);
      }
    }
    #pragma unroll
    for (int kt = 0; kt < 4; kt++) {
      short8 ap = *(const short8*)&Ps[w][l16 * 136 + kt * 32 + quad * 8];
      #pragma unroll
      for (int dt = 0; dt < 4; dt++) {
        int vrow = dt * 16 + l16;
        int c = (kt * 4 + quad) ^ l16;
        short8 bv = *(const short8*)&Vs[vrow * 128 + c * 8];
        accO[dt] = mfma16(ap, bv, accO[dt]);
      }
    }
  }
  #pragma unroll
  for (int r = 0; r < 4; r++) {
    #pragma unroll
    for (int o = 1; o < 16; o <<= 1) lsum[r] += __shfl_xor(lsum[r], o);
  }
  const size_t sb = (size_t)(sp * 24 + bh) * 1024;
  #pragma unroll
  for (int r = 0; r < 4; r++) {
    int lr = qrow0 + quad * 4 + r;
    if (l16 == 0) pl[sb + lr] = lsum[r];
    #pragma unroll
    for (int dt = 0; dt < 4; dt++)
      po[(sb + lr) * 64 + dt * 16 + l16] = accO[dt][r];
  }
}

// combine 2 splits (plain sums; fixed shift means no max merge): wave per row.
__global__ __launch_bounds__(256) void attn_comb(const float* __restrict__ po,
                                                 const float* __restrict__ pl,
                                                 u16* __restrict__ obuf) {
  int w = threadIdx.x >> 6, lane = threadIdx.x & 63;
  int gr = blockIdx.x * 4 + w;            // [0, 24576)
  int bh = gr >> 10, l = gr & 1023;
  float num = 0.f, den = 0.f;
  #pragma unroll
  for (int s = 0; s < 2; s++) {
    num += po[((size_t)(s * 24 + bh) * 1024 + l) * 64 + lane];
    den += pl[(size_t)(s * 24 + bh) * 1024 + l];
  }
  int b = bh / 12, h = bh % 12;
  obuf[((size_t)(b * 1024 + l)) * 768 + h * 64 + lane] = f2bf(num / den);
}

// ---------------------------------------------------------------------------
// GEMM: C(M,N) = A(M,K) @ Bt(N,K)^T, bf16 in, fp32 acc.
// Tile 64(M) x BN(N) x 32(K); 4 waves, each computes 32 x BN/2.
// EPI 0: +bias -> Cf (or Cb).  1: +bias +cond[row>>10] -> Cf.
// EPI 2: +bias +extra[row,col] -> Cf and Cb.  3: gelu(+bias) -> Cb.
template <int EPI, int BN>
__global__ __launch_bounds__(256) void gemm_bt(const u16* __restrict__ A,
                                               const u16* __restrict__ Bt,
                                               const float* __restrict__ bias,
                                               const float* extra,
                                               float* Cf, u16* Cb, int M, int N, int K) {
  constexpr int ROWS = 64 + BN;
  constexpr int NTW  = BN / 32;        // n-frags per wave
  constexpr int PC   = ROWS / 64;      // staging chunks per wave
  __shared__ __align__(16) u16 S[ROWS * 32];
  u16* As = S;
  u16* Bs = S + 64 * 32;
  const int t = threadIdx.x;
  const int lane = t & 63, w = t >> 6;
  const int quad = lane >> 4, l16 = lane & 15;
  const int m0 = blockIdx.y * 64, n0 = blockIdx.x * BN;
  const int wm = (w >> 1) * 32, wn = (w & 1) * (BN / 2);
  floatx4 acc[2][NTW];
  #pragma unroll
  for (int i = 0; i < 2; i++)
    #pragma unroll
    for (int j = 0; j < NTW; j++) acc[i][j] = (floatx4){0.f, 0.f, 0.f, 0.f};

  // staging: ROWS/16 chunks of 16 rows x 32 cols; chunk c<4 -> A rows, else B rows.
  const u16* gp[PC];
  u16* lp[PC];
  #pragma unroll
  for (int j = 0; j < PC; j++) {
    int c = w * PC + j;
    int r = lane >> 2;
    const u16* base = (c < 4) ? (A + (size_t)(m0 + c * 16 + r) * K)
                              : (Bt + (size_t)(n0 + (c - 4) * 16 + r) * K);
    gp[j] = base + (lane & 3) * 8;
    lp[j] = S + c * 16 * 32;
  }

  for (int k0 = 0; k0 < K; k0 += 32) {
    #pragma unroll
    for (int j = 0; j < PC; j++) glds16(gp[j] + k0, lp[j]);
    __syncthreads();
    short8 af[2], bfr[NTW];
    #pragma unroll
    for (int mt = 0; mt < 2; mt++)
      af[mt] = *(const short8*)&As[(wm + mt * 16 + l16) * 32 + quad * 8];
    #pragma unroll
    for (int nt = 0; nt < NTW; nt++)
      bfr[nt] = *(const short8*)&Bs[(wn + nt * 16 + l16) * 32 + quad * 8];
    #pragma unroll
    for (int mt = 0; mt < 2; mt++)
      #pragma unroll
      for (int nt = 0; nt < NTW; nt++)
        acc[mt][nt] = mfma16(af[mt], bfr[nt], acc[mt][nt]);
    __syncthreads();
  }

  #pragma unroll
  for (int mt = 0; mt < 2; mt++) {
    #pragma unroll
    for (int nt = 0; nt < NTW; nt++) {
      int col = n0 + wn + nt * 16 + l16;
      float bcol = bias ? bias[col] : 0.f;
      #pragma unroll
      for (int r = 0; r < 4; r++) {
        int row = m0 + wm + mt * 16 + quad * 4 + r;
        float v = acc[mt][nt][r] + bcol;
        if (EPI == 1) v += extra[(row >> 10) * N + col];
        if (EPI == 2) v += extra[(size_t)row * N + col];
        if (EPI == 3) v = 0.5f * v * (1.f + erff(v * 0.70710678118654752f));
        if (Cf) Cf[(size_t)row * N + col] = v;
        if (Cb) Cb[(size_t)row * N + col] = f2bf(v);
      }
    }
  }
}

// ---------------------------------------------------------------------------
extern "C" void kernel_launch(void* const* d_in, const int* in_sizes, int n_in,
                              void* d_out, int out_size, void* d_ws, size_t ws_size,
                              hipStream_t stream) {
  const float* sf   = (const float*)d_in[0];
  const float* ce   = (const float*)d_in[2];
  const float* sw   = (const float*)d_in[3];
  const float* sb   = (const float*)d_in[4];
  const float* cw   = (const float*)d_in[5];
  const float* cb   = (const float*)d_in[6];
  const float* ln1g = (const float*)d_in[7];
  const float* ln1b = (const float*)d_in[8];
  const float* qkvw = (const float*)d_in[9];
  const float* qsc  = (const float*)d_in[10];
  const float* ksc  = (const float*)d_in[11];
  const float* pw   = (const float*)d_in[12];
  const float* pb   = (const float*)d_in[13];
  const float* ln2g = (const float*)d_in[16];
  const float* ln2b = (const float*)d_in[17];
  const float* w1   = (const float*)d_in[18];
  const float* b1   = (const float*)d_in[19];
  const float* w2   = (const float*)d_in[20];
  const float* b2   = (const float*)d_in[21];
  const float* ow   = (const float*)d_in[22];
  const float* ob   = (const float*)d_in[23];

  char* p = (char*)d_ws;
  auto alloc = [&](size_t bytes) { char* r = p; p += (bytes + 255) & ~(size_t)255; return r; };
  float* pet  = (float*)alloc((size_t)1024 * 32 * 2 * 4);
  u16* swT    = (u16*)alloc((size_t)768 * 768 * 2);
  u16* owT    = (u16*)alloc((size_t)768 * 768 * 2);
  u16* qkvT   = (u16*)alloc((size_t)6 * 2304 * 768 * 2);
  u16* pwT    = (u16*)alloc((size_t)6 * 768 * 768 * 2);
  u16* w1T    = (u16*)alloc((size_t)6 * 3072 * 768 * 2);
  u16* w2T    = (u16*)alloc((size_t)6 * 768 * 3072 * 2);
  u16* sfb    = (u16*)alloc((size_t)2048 * 768 * 2);
  float* cpar = (float*)alloc((size_t)32 * 768 * 4);
  float* cond = (float*)alloc((size_t)2 * 768 * 4);
  float* x    = (float*)alloc((size_t)2048 * 768 * 4);
  u16* xb     = (u16*)alloc((size_t)2048 * 768 * 2);
  u16* h      = (u16*)alloc((size_t)2048 * 768 * 2);
  float* qkv  = (float*)alloc((size_t)2048 * 2304 * 4);
  u16* qbuf   = (u16*)alloc((size_t)2048 * 768 * 2);
  u16* kbuf   = (u16*)alloc((size_t)2048 * 768 * 2);
  u16* vtb    = (u16*)alloc((size_t)2048 * 768 * 2);
  u16* obuf   = (u16*)alloc((size_t)2048 * 768 * 2);
  u16* gbuf   = (u16*)alloc((size_t)2048 * 3072 * 2);
  float* po   = (float*)alloc((size_t)2 * 24 * 1024 * 64 * 4);
  float* pl   = (float*)alloc((size_t)2 * 24 * 1024 * 4);

  pe_kernel<<<128, 256, 0, stream>>>(pet);
  twt_kernel<<<dim3(24, 24, 1), 256, 0, stream>>>(sw, swT, 768, 768);
  twt_kernel<<<dim3(24, 24, 1), 256, 0, stream>>>(ow, owT, 768, 768);
  twt_kernel<<<dim3(72, 24, 6), 256, 0, stream>>>(qkvw, qkvT, 768, 2304);
  twt_kernel<<<dim3(24, 24, 6), 256, 0, stream>>>(pw, pwT, 768, 768);
  twt_kernel<<<dim3(96, 24, 6), 256, 0, stream>>>(w1, w1T, 768, 3072);
  twt_kernel<<<dim3(24, 96, 6), 256, 0, stream>>>(w2, w2T, 3072, 768);
  cvt_kernel<<<(2048 * 768) / 256, 256, 0, stream>>>(sf, sfb, 2048 * 768);
  condp_kernel<<<dim3(3, 16), 256, 0, stream>>>(ce, cw, cpar);
  condr_kernel<<<6, 256, 0, stream>>>(cpar, cb, cond);

  gemm_bt<1, 64><<<dim3(12, 32), 256, 0, stream>>>(sfb, swT, sb, cond, x, nullptr, 2048, 768, 768);

  for (int i = 0; i < 6; i++) {
    ln_kernel<<<2048, 256, 0, stream>>>(x, ln1g + i * 768, ln1b + i * 768, h);
    gemm_bt<0, 128><<<dim3(18, 32), 256, 0, stream>>>(h, qkvT + (size_t)i * 2304 * 768,
                                                      nullptr, nullptr, qkv, nullptr, 2048, 2304, 768);
    ropeq_kernel<<<6144, 256, 0, stream>>>(qkv, qsc + i * 64, ksc + i * 64, pet, qbuf, kbuf);
    vtrans_kernel<<<dim3(16, 24), 256, 0, stream>>>(qkv, vtb);
    attn_split<<<dim3(16, 24, 2), 256, 0, stream>>>(qbuf, kbuf, vtb, po, pl);
    attn_comb<<<6144, 256, 0, stream>>>(po, pl, obuf);
    gemm_bt<2, 64><<<dim3(12, 32), 256, 0, stream>>>(obuf, pwT + (size_t)i * 768 * 768,
                                                     pb + i * 768, x, x, xb, 2048, 768, 768);
    ln_kernel<<<2048, 256, 0, stream>>>(x, ln2g + i * 768, ln2b + i * 768, h);
    gemm_bt<3, 128><<<dim3(24, 32), 256, 0, stream>>>(h, w1T + (size_t)i * 3072 * 768,
                                                      b1 + i * 3072, nullptr, nullptr, gbuf, 2048, 3072, 768);
    gemm_bt<2, 64><<<dim3(12, 32), 256, 0, stream>>>(gbuf, w2T + (size_t)i * 768 * 3072,
                                                     b2 + i * 768, x, x, xb, 2048, 768, 3072);
  }
  gemm_bt<0, 64><<<dim3(12, 32), 256, 0, stream>>>(xb, owT, ob, nullptr, (float*)d_out, nullptr,
                                                   2048, 768, 768);
}

// Round 6
// 1120.340 us; speedup vs baseline: 1.2881x; 1.0690x over previous
//
#include <hip/hip_runtime.h>
#include <hip/hip_bf16.h>
#include <cstdint>
#include <cstddef>

typedef unsigned short u16;
using short8  = __attribute__((ext_vector_type(8))) short;
using floatx4 = __attribute__((ext_vector_type(4))) float;

typedef __attribute__((address_space(1))) void gvoid;
typedef __attribute__((address_space(3))) void svoid;

__device__ __forceinline__ u16 f2bf(float f) {
  __hip_bfloat16 h = __float2bfloat16(f);
  return __builtin_bit_cast(u16, h);
}

__device__ __forceinline__ floatx4 mfma16(short8 a, short8 b, floatx4 c) {
  return __builtin_amdgcn_mfma_f32_16x16x32_bf16(a, b, c, 0, 0, 0);
}

// async 16B/lane global->LDS; lds base must be wave-uniform (lane i lands at base + i*16B)
__device__ __forceinline__ void glds16(const u16* g, u16* l) {
  __builtin_amdgcn_global_load_lds((gvoid*)g, (svoid*)l, 16, 0, 0);
}

// ---------------------------------------------------------------------------
// pe table: per (l, j) cos/sin.  j<16: x=l%32 rotations; j>=16: y=l/32.
__global__ void pe_kernel(float* __restrict__ pet) {
  int t = blockIdx.x * 256 + threadIdx.x;   // 1024*32
  if (t >= 32768) return;
  int l = t >> 5, j = t & 31;
  float pos   = (j < 16) ? (float)(l & 31) : (float)(l >> 5);
  float omega = powf(10000.f, -(float)(j & 15) / 16.f);
  float a = pos * omega;
  pet[2 * t]     = cosf(a);
  pet[2 * t + 1] = sinf(a);
}

// ---------------------------------------------------------------------------
// weight transpose + bf16 cast: in fp32 (K,N) row-major -> out bf16 (N,K)
// blockIdx.z = layer (stride K*N elements both sides)
__global__ __launch_bounds__(256) void twt_kernel(const float* __restrict__ in,
                                                  u16* __restrict__ out, int K, int N) {
  size_t lofs = (size_t)blockIdx.z * K * N;
  in  += lofs;
  out += lofs;
  __shared__ float tile[32][33];
  int bx = blockIdx.x;           // over N
  int by = blockIdx.y;           // over K
  int tx = threadIdx.x & 31, ty = threadIdx.x >> 5;  // 32 x 8
  #pragma unroll
  for (int p = 0; p < 4; p++) {
    int k = by * 32 + ty + p * 8;
    tile[ty + p * 8][tx] = in[(size_t)k * N + bx * 32 + tx];
  }
  __syncthreads();
  #pragma unroll
  for (int p = 0; p < 4; p++) {
    int n = bx * 32 + ty + p * 8;
    out[(size_t)n * K + by * 32 + tx] = f2bf(tile[tx][ty + p * 8]);
  }
}

// fp32 -> bf16 elementwise
__global__ void cvt_kernel(const float* __restrict__ in, u16* __restrict__ out, int n) {
  int i = blockIdx.x * 256 + threadIdx.x;
  if (i < n) out[i] = f2bf(in[i]);
}

// cond projection, stage 1: partial[chunk][b][d] over 96-k chunks
__global__ __launch_bounds__(256) void condp_kernel(const float* __restrict__ ce,
                                                    const float* __restrict__ w,
                                                    float* __restrict__ partial) {
  int d = blockIdx.x * 256 + threadIdx.x;  // 768
  int c = blockIdx.y;                      // 16
  #pragma unroll
  for (int b = 0; b < 2; b++) {
    float acc = 0.f;
    #pragma unroll 4
    for (int k = c * 96; k < c * 96 + 96; k++) acc += ce[b * 1536 + k] * w[(size_t)k * 768 + d];
    partial[(size_t)(c * 2 + b) * 768 + d] = acc;
  }
}

// cond projection, stage 2: reduce 16 partials + bias
__global__ __launch_bounds__(256) void condr_kernel(const float* __restrict__ partial,
                                                    const float* __restrict__ bias,
                                                    float* __restrict__ out) {
  int t = blockIdx.x * 256 + threadIdx.x;  // 1536
  int b = t / 768, d = t % 768;
  float acc = bias[d];
  #pragma unroll
  for (int c = 0; c < 16; c++) acc += partial[(size_t)(c * 2 + b) * 768 + d];
  out[b * 768 + d] = acc;
}

// ---------------------------------------------------------------------------
// layernorm: x fp32 (rows,768) -> out bf16
__global__ __launch_bounds__(256) void ln_kernel(const float* __restrict__ x,
                                                 const float* __restrict__ g,
                                                 const float* __restrict__ b,
                                                 u16* __restrict__ out) {
  int row = blockIdx.x;
  const float* xr = x + (size_t)row * 768;
  int t = threadIdx.x;
  float v0 = xr[t], v1 = xr[t + 256], v2 = xr[t + 512];
  float s = v0 + v1 + v2, s2 = v0 * v0 + v1 * v1 + v2 * v2;
  #pragma unroll
  for (int o = 32; o >= 1; o >>= 1) { s += __shfl_xor(s, o); s2 += __shfl_xor(s2, o); }
  __shared__ float red[8];
  int w = t >> 6, lane = t & 63;
  if (lane == 0) { red[w] = s; red[4 + w] = s2; }
  __syncthreads();
  s  = red[0] + red[1] + red[2] + red[3];
  s2 = red[4] + red[5] + red[6] + red[7];
  float mean = s * (1.f / 768.f);
  float var  = s2 * (1.f / 768.f) - mean * mean;
  float rstd = rsqrtf(var + 1e-5f);
  u16* orow = out + (size_t)row * 768;
  orow[t]       = f2bf((v0 - mean) * rstd * g[t] + b[t]);
  orow[t + 256] = f2bf((v1 - mean) * rstd * g[t + 256] + b[t + 256]);
  orow[t + 512] = f2bf((v2 - mean) * rstd * g[t + 512] + b[t + 512]);
}

// ---------------------------------------------------------------------------
// rmsnorm + rope on q,k.  One 64-lane group per (b,l,h).  attn_scale folded into q.
__global__ __launch_bounds__(256) void ropeq_kernel(const float* __restrict__ qkv,
                                                    const float* __restrict__ qs,
                                                    const float* __restrict__ ks,
                                                    const float* __restrict__ pet,
                                                    u16* __restrict__ qb, u16* __restrict__ kb) {
  int gid = blockIdx.x * 4 + (threadIdx.x >> 6);  // (b*1024+l)*12 + h
  int lane = threadIdx.x & 63;
  int h = gid % 12, bl = gid / 12;
  int l = bl & 1023, b = bl >> 10;
  const float* qp = qkv + ((size_t)(b * 1024 + l) * 3 + 0) * 768 + h * 64;
  const float* kp = qp + 768;
  float q = qp[lane], k = kp[lane];
  float sq = q * q, sk = k * k;
  #pragma unroll
  for (int o = 1; o < 64; o <<= 1) { sq += __shfl_xor(sq, o); sk += __shfl_xor(sk, o); }
  q *= rsqrtf(sq * (1.f / 64.f) + 1e-6f) * qs[lane];
  k *= rsqrtf(sk * (1.f / 64.f) + 1e-6f) * ks[lane];
  int j = lane >> 1;
  float c = pet[(l * 32 + j) * 2], s = pet[(l * 32 + j) * 2 + 1];
  float qo = __shfl_xor(q, 1), ko = __shfl_xor(k, 1);
  float qr = (lane & 1) ? (s * qo + c * q) : (c * q - s * qo);
  float kr = (lane & 1) ? (s * ko + c * k) : (c * k - s * ko);
  int bh = b * 12 + h;
  qb[((size_t)bh * 1024 + l) * 64 + lane] = f2bf(qr * 0.125f);
  kb[((size_t)bh * 1024 + l) * 64 + lane] = f2bf(kr);
}

// v: (b,l,h,d) slice of qkv -> vt bf16 (bh, d, l)
__global__ __launch_bounds__(256) void vtrans_kernel(const float* __restrict__ qkv,
                                                     u16* __restrict__ vt) {
  int lt = blockIdx.x, bh = blockIdx.y;
  int b = bh / 12, h = bh % 12;
  __shared__ float tile[64][65];
  int t = threadIdx.x, c = t & 63, r0 = t >> 6;
  #pragma unroll
  for (int p = 0; p < 16; p++) {
    int lr = p * 4 + r0;
    tile[lr][c] = qkv[((size_t)(b * 1024 + lt * 64 + lr) * 3 + 2) * 768 + h * 64 + c];
  }
  __syncthreads();
  #pragma unroll
  for (int p = 0; p < 16; p++) {
    int d = p * 4 + r0;
    vt[((size_t)bh * 64 + d) * 1024 + lt * 64 + c] = f2bf(tile[c][d]);
  }
}

// ---------------------------------------------------------------------------
// flash attention, split-KV, fixed-shift softmax (scores in [-8,8] after rmsnorm),
// block-shared LDS staging of K/V via global_load_lds with XOR chunk swizzle.
// grid (qt, bh, split=2); block: 64 q rows x 512 kv (4 tiles of 128).
// 4 waves, wave owns 16 q rows.  Writes unnormalized partial O + row sums.
__global__ __launch_bounds__(256) void attn_split(const u16* __restrict__ qb,
                                                  const u16* __restrict__ kbuf,
                                                  const u16* __restrict__ vt,
                                                  float* __restrict__ po,
                                                  float* __restrict__ pl) {
  const int qt = blockIdx.x, bh = blockIdx.y, sp = blockIdx.z;
  const int lane = threadIdx.x & 63, w = threadIdx.x >> 6;
  const int quad = lane >> 4, l16 = lane & 15;
  __shared__ __align__(16) u16 Ks[128 * 64];
  __shared__ __align__(16) u16 Vs[64 * 128];
  __shared__ __align__(16) u16 Ps[4][16 * 136];
  const u16* Q  = qb   + (size_t)bh * 1024 * 64;
  const u16* Kp = kbuf + (size_t)bh * 1024 * 64;
  const u16* Vp = vt   + (size_t)bh * 64 * 1024;
  const int qrow0 = qt * 64 + w * 16;
  short8 aq0, aq1;
  {
    const u16* qp = Q + (size_t)(qrow0 + l16) * 64 + quad * 8;
    aq0 = *(const short8*)qp;
    aq1 = *(const short8*)(qp + 32);
  }
  floatx4 accO[4];
  #pragma unroll
  for (int i = 0; i < 4; i++) accO[i] = (floatx4){0.f, 0.f, 0.f, 0.f};
  float lsum[4] = {0.f, 0.f, 0.f, 0.f};

  const int krow_in = (lane >> 3);
  const int kchunk  = lane & 7;
  const int vrow_in = (lane >> 4);
  const int vchunk  = lane & 15;

  for (int nt = 0; nt < 4; ++nt) {
    const int kb0 = sp * 512 + nt * 128;
    __syncthreads();
    #pragma unroll
    for (int j = 0; j < 4; j++) {
      int r = w * 32 + j * 8 + krow_in;
      int g = kchunk ^ (r & 7);
      glds16(Kp + (size_t)(kb0 + r) * 64 + g * 8, Ks + (w * 32 + j * 8) * 64);
    }
    #pragma unroll
    for (int j = 0; j < 4; j++) {
      int r = w * 16 + j * 4 + vrow_in;
      int g = vchunk ^ (r & 15);
      glds16(Vp + (size_t)r * 1024 + kb0 + g * 8, Vs + (w * 16 + j * 4) * 128);
    }
    __syncthreads();

    floatx4 s[8];
    #pragma unroll
    for (int n = 0; n < 8; n++) {
      int row = n * 16 + l16;
      int c0 = quad ^ (l16 & 7);
      short8 b0 = *(const short8*)&Ks[row * 64 + c0 * 8];
      short8 b1 = *(const short8*)&Ks[row * 64 + (c0 ^ 4) * 8];
      floatx4 z = (floatx4){0.f, 0.f, 0.f, 0.f};
      z = mfma16(aq0, b0, z);
      s[n] = mfma16(aq1, b1, z);
    }
    #pragma unroll
    for (int n = 0; n < 8; n++) {
      #pragma unroll
      for (int r = 0; r < 4; r++) {
        float pv = __expf(s[n][r] - 8.f);
        lsum[r] += pv;
        Ps[w][(quad * 4 + r) * 136 + n * 16 + l16] = f2bf(pv);
      }
    }
    #pragma unroll
    for (int kt = 0; kt < 4; kt++) {
      short8 ap = *(const short8*)&Ps[w][l16 * 136 + kt * 32 + quad * 8];
      #pragma unroll
      for (int dt = 0; dt < 4; dt++) {
        int vrow = dt * 16 + l16;
        int c = (kt * 4 + quad) ^ l16;
        short8 bv = *(const short8*)&Vs[vrow * 128 + c * 8];
        accO[dt] = mfma16(ap, bv, accO[dt]);
      }
    }
  }
  #pragma unroll
  for (int r = 0; r < 4; r++) {
    #pragma unroll
    for (int o = 1; o < 16; o <<= 1) lsum[r] += __shfl_xor(lsum[r], o);
  }
  const size_t sb = (size_t)(sp * 24 + bh) * 1024;
  #pragma unroll
  for (int r = 0; r < 4; r++) {
    int lr = qrow0 + quad * 4 + r;
    if (l16 == 0) pl[sb + lr] = lsum[r];
    #pragma unroll
    for (int dt = 0; dt < 4; dt++)
      po[(sb + lr) * 64 + dt * 16 + l16] = accO[dt][r];
  }
}

// combine 2 splits: wave per row.
__global__ __launch_bounds__(256) void attn_comb(const float* __restrict__ po,
                                                 const float* __restrict__ pl,
                                                 u16* __restrict__ obuf) {
  int w = threadIdx.x >> 6, lane = threadIdx.x & 63;
  int gr = blockIdx.x * 4 + w;            // [0, 24576)
  int bh = gr >> 10, l = gr & 1023;
  float num = 0.f, den = 0.f;
  #pragma unroll
  for (int s = 0; s < 2; s++) {
    num += po[((size_t)(s * 24 + bh) * 1024 + l) * 64 + lane];
    den += pl[(size_t)(s * 24 + bh) * 1024 + l];
  }
  int b = bh / 12, h = bh % 12;
  obuf[((size_t)(b * 1024 + l)) * 768 + h * 64 + lane] = f2bf(num / den);
}

// ---------------------------------------------------------------------------
// GEMM: C(M,N) = A(M,K) @ Bt(N,K)^T, bf16 in, fp32 acc.
// Software-pipelined: BK=64, VGPR-staged depth-2 prefetch, ping-pong LDS,
// ONE barrier per K-iteration (writes go to the buffer nobody is reading).
// Tile 64(M) x BN(N); 4 waves, each computes 32 x BN/2.
// EPI 0: +bias -> Cf (or Cb).  1: +bias +cond[row>>10] -> Cf.
// EPI 2: +bias +extra[row,col] -> Cf and Cb.  3: gelu(+bias) -> Cb.
template <int EPI, int BN>
__global__ __launch_bounds__(256) void gemm_bt(const u16* __restrict__ A,
                                               const u16* __restrict__ Bt,
                                               const float* __restrict__ bias,
                                               const float* extra,
                                               float* Cf, u16* Cb, int M, int N, int K) {
  constexpr int ROWS = 64 + BN;          // A rows then B rows
  constexpr int LDW  = 72;               // padded row stride in u16 (144B, 16B-aligned)
  constexpr int NCH  = ROWS * 8 / 256;   // 16B chunks per thread per K-step
  constexpr int NTW  = BN / 32;          // n-frags per wave
  __shared__ __align__(16) u16 S[2][ROWS * LDW];
  const int t = threadIdx.x;
  const int lane = t & 63, w = t >> 6;
  const int quad = lane >> 4, l16 = lane & 15;
  const int m0 = blockIdx.y * 64, n0 = blockIdx.x * BN;
  const int wm = (w >> 1) * 32, wn = (w & 1) * (BN / 2);
  floatx4 acc[2][NTW];
  #pragma unroll
  for (int i = 0; i < 2; i++)
    #pragma unroll
    for (int j = 0; j < NTW; j++) acc[i][j] = (floatx4){0.f, 0.f, 0.f, 0.f};

  // staging descriptors: chunk idx = j*256+t -> row=idx>>3, col-chunk=idx&7
  const u16* gsrc[NCH];
  int laddr[NCH];
  #pragma unroll
  for (int j = 0; j < NCH; j++) {
    int idx = j * 256 + t;
    int row = idx >> 3, c = idx & 7;
    const u16* base = (row < 64) ? (A + (size_t)(m0 + row) * K)
                                 : (Bt + (size_t)(n0 + row - 64) * K);
    gsrc[j] = base + c * 8;
    laddr[j] = row * LDW + c * 8;
  }
  short8 stg0[NCH], stg1[NCH];

  const int NIT = K / 64;   // always even here (12 or 48)

  #pragma unroll
  for (int j = 0; j < NCH; j++) stg0[j] = *(const short8*)(gsrc[j]);
  #pragma unroll
  for (int j = 0; j < NCH; j++) stg1[j] = *(const short8*)(gsrc[j] + 64);
  #pragma unroll
  for (int j = 0; j < NCH; j++) *(short8*)&S[0][laddr[j]] = stg0[j];
  __syncthreads();

  auto compute = [&](int buf) {
    #pragma unroll
    for (int kk = 0; kk < 2; kk++) {
      short8 af[2], bfr[NTW];
      #pragma unroll
      for (int mt = 0; mt < 2; mt++)
        af[mt] = *(const short8*)&S[buf][(wm + mt * 16 + l16) * LDW + kk * 32 + quad * 8];
      #pragma unroll
      for (int nt = 0; nt < NTW; nt++)
        bfr[nt] = *(const short8*)&S[buf][(64 + wn + nt * 16 + l16) * LDW + kk * 32 + quad * 8];
      #pragma unroll
      for (int mt = 0; mt < 2; mt++)
        #pragma unroll
        for (int nt = 0; nt < NTW; nt++)
          acc[mt][nt] = mfma16(af[mt], bfr[nt], acc[mt][nt]);
    }
  };

  for (int it = 0; it < NIT; it += 2) {
    // even: compute buf0 (k=it), prefetch k=it+2 -> stg0, write stg1 (k=it+1) -> buf1
    if (it + 2 < NIT) {
      #pragma unroll
      for (int j = 0; j < NCH; j++) stg0[j] = *(const short8*)(gsrc[j] + (it + 2) * 64);
    }
    compute(0);
    #pragma unroll
    for (int j = 0; j < NCH; j++) *(short8*)&S[1][laddr[j]] = stg1[j];
    __syncthreads();
    // odd: compute buf1 (k=it+1), prefetch k=it+3 -> stg1, write stg0 (k=it+2) -> buf0
    if (it + 3 < NIT) {
      #pragma unroll
      for (int j = 0; j < NCH; j++) stg1[j] = *(const short8*)(gsrc[j] + (it + 3) * 64);
    }
    compute(1);
    if (it + 2 < NIT) {
      #pragma unroll
      for (int j = 0; j < NCH; j++) *(short8*)&S[0][laddr[j]] = stg0[j];
    }
    __syncthreads();
  }

  #pragma unroll
  for (int mt = 0; mt < 2; mt++) {
    #pragma unroll
    for (int nt = 0; nt < NTW; nt++) {
      int col = n0 + wn + nt * 16 + l16;
      float bcol = bias ? bias[col] : 0.f;
      #pragma unroll
      for (int r = 0; r < 4; r++) {
        int row = m0 + wm + mt * 16 + quad * 4 + r;
        float v = acc[mt][nt][r] + bcol;
        if (EPI == 1) v += extra[(row >> 10) * N + col];
        if (EPI == 2) v += extra[(size_t)row * N + col];
        if (EPI == 3) v = 0.5f * v * (1.f + erff(v * 0.70710678118654752f));
        if (Cf) Cf[(size_t)row * N + col] = v;
        if (Cb) Cb[(size_t)row * N + col] = f2bf(v);
      }
    }
  }
}

// ---------------------------------------------------------------------------
extern "C" void kernel_launch(void* const* d_in, const int* in_sizes, int n_in,
                              void* d_out, int out_size, void* d_ws, size_t ws_size,
                              hipStream_t stream) {
  const float* sf   = (const float*)d_in[0];
  const float* ce   = (const float*)d_in[2];
  const float* sw   = (const float*)d_in[3];
  const float* sb   = (const float*)d_in[4];
  const float* cw   = (const float*)d_in[5];
  const float* cb   = (const float*)d_in[6];
  const float* ln1g = (const float*)d_in[7];
  const float* ln1b = (const float*)d_in[8];
  const float* qkvw = (const float*)d_in[9];
  const float* qsc  = (const float*)d_in[10];
  const float* ksc  = (const float*)d_in[11];
  const float* pw   = (const float*)d_in[12];
  const float* pb   = (const float*)d_in[13];
  const float* ln2g = (const float*)d_in[16];
  const float* ln2b = (const float*)d_in[17];
  const float* w1   = (const float*)d_in[18];
  const float* b1   = (const float*)d_in[19];
  const float* w2   = (const float*)d_in[20];
  const float* b2   = (const float*)d_in[21];
  const float* ow   = (const float*)d_in[22];
  const float* ob   = (const float*)d_in[23];

  char* p = (char*)d_ws;
  auto alloc = [&](size_t bytes) { char* r = p; p += (bytes + 255) & ~(size_t)255; return r; };
  float* pet  = (float*)alloc((size_t)1024 * 32 * 2 * 4);
  u16* swT    = (u16*)alloc((size_t)768 * 768 * 2);
  u16* owT    = (u16*)alloc((size_t)768 * 768 * 2);
  u16* qkvT   = (u16*)alloc((size_t)6 * 2304 * 768 * 2);
  u16* pwT    = (u16*)alloc((size_t)6 * 768 * 768 * 2);
  u16* w1T    = (u16*)alloc((size_t)6 * 3072 * 768 * 2);
  u16* w2T    = (u16*)alloc((size_t)6 * 768 * 3072 * 2);
  u16* sfb    = (u16*)alloc((size_t)2048 * 768 * 2);
  float* cpar = (float*)alloc((size_t)32 * 768 * 4);
  float* cond = (float*)alloc((size_t)2 * 768 * 4);
  float* x    = (float*)alloc((size_t)2048 * 768 * 4);
  u16* xb     = (u16*)alloc((size_t)2048 * 768 * 2);
  u16* h      = (u16*)alloc((size_t)2048 * 768 * 2);
  float* qkv  = (float*)alloc((size_t)2048 * 2304 * 4);
  u16* qbuf   = (u16*)alloc((size_t)2048 * 768 * 2);
  u16* kbuf   = (u16*)alloc((size_t)2048 * 768 * 2);
  u16* vtb    = (u16*)alloc((size_t)2048 * 768 * 2);
  u16* obuf   = (u16*)alloc((size_t)2048 * 768 * 2);
  u16* gbuf   = (u16*)alloc((size_t)2048 * 3072 * 2);
  float* po   = (float*)alloc((size_t)2 * 24 * 1024 * 64 * 4);
  float* pl   = (float*)alloc((size_t)2 * 24 * 1024 * 4);

  pe_kernel<<<128, 256, 0, stream>>>(pet);
  twt_kernel<<<dim3(24, 24, 1), 256, 0, stream>>>(sw, swT, 768, 768);
  twt_kernel<<<dim3(24, 24, 1), 256, 0, stream>>>(ow, owT, 768, 768);
  twt_kernel<<<dim3(72, 24, 6), 256, 0, stream>>>(qkvw, qkvT, 768, 2304);
  twt_kernel<<<dim3(24, 24, 6), 256, 0, stream>>>(pw, pwT, 768, 768);
  twt_kernel<<<dim3(96, 24, 6), 256, 0, stream>>>(w1, w1T, 768, 3072);
  twt_kernel<<<dim3(24, 96, 6), 256, 0, stream>>>(w2, w2T, 3072, 768);
  cvt_kernel<<<(2048 * 768) / 256, 256, 0, stream>>>(sf, sfb, 2048 * 768);
  condp_kernel<<<dim3(3, 16), 256, 0, stream>>>(ce, cw, cpar);
  condr_kernel<<<6, 256, 0, stream>>>(cpar, cb, cond);

  gemm_bt<1, 64><<<dim3(12, 32), 256, 0, stream>>>(sfb, swT, sb, cond, x, nullptr, 2048, 768, 768);

  for (int i = 0; i < 6; i++) {
    ln_kernel<<<2048, 256, 0, stream>>>(x, ln1g + i * 768, ln1b + i * 768, h);
    gemm_bt<0, 128><<<dim3(18, 32), 256, 0, stream>>>(h, qkvT + (size_t)i * 2304 * 768,
                                                      nullptr, nullptr, qkv, nullptr, 2048, 2304, 768);
    ropeq_kernel<<<6144, 256, 0, stream>>>(qkv, qsc + i * 64, ksc + i * 64, pet, qbuf, kbuf);
    vtrans_kernel<<<dim3(16, 24), 256, 0, stream>>>(qkv, vtb);
    attn_split<<<dim3(16, 24, 2), 256, 0, stream>>>(qbuf, kbuf, vtb, po, pl);
    attn_comb<<<6144, 256, 0, stream>>>(po, pl, obuf);
    gemm_bt<2, 64><<<dim3(12, 32), 256, 0, stream>>>(obuf, pwT + (size_t)i * 768 * 768,
                                                     pb + i * 768, x, x, xb, 2048, 768, 768);
    ln_kernel<<<2048, 256, 0, stream>>>(x, ln2g + i * 768, ln2b + i * 768, h);
    gemm_bt<3, 128><<<dim3(24, 32), 256, 0, stream>>>(h, w1T + (size_t)i * 3072 * 768,
                                                      b1 + i * 3072, nullptr, nullptr, gbuf, 2048, 3072, 768);
    gemm_bt<2, 64><<<dim3(12, 32), 256, 0, stream>>>(gbuf, w2T + (size_t)i * 768 * 3072,
                                                     b2 + i * 768, x, x, xb, 2048, 768, 3072);
  }
  gemm_bt<0, 64><<<dim3(12, 32), 256, 0, stream>>>(xb, owT, ob, nullptr, (float*)d_out, nullptr,
                                                   2048, 768, 768);
}